// Round 6
// baseline (683.200 us; speedup 1.0000x reference)
//
#include <hip/hip_runtime.h>
#include <hip/hip_bf16.h>

#define FDIM 128

typedef __attribute__((ext_vector_type(8))) short short8v;   // 8 bf16 in 4 VGPRs
typedef __attribute__((ext_vector_type(4))) float f32x4;

__device__ __forceinline__ short f2bf(float f) {             // RNE f32 -> bf16 bits
    unsigned u = __float_as_uint(f);
    u += 0x7FFFu + ((u >> 16) & 1u);
    return (short)(u >> 16);
}

// ---- y = x @ W via MFMA bf16.  Wave: 16 rows x 64 cols; block: 32 rows x 128 cols.
__global__ __launch_bounds__(256)
void gemm_mfma(const float* __restrict__ x, const float* __restrict__ W,
               unsigned short* __restrict__ y, int nrows) {
    const int lane = threadIdx.x & 63;
    const int wid  = threadIdx.x >> 6;         // 0..3
    const int colHalf = wid & 1;               // cols 0-63 / 64-127
    const int rowSub  = wid >> 1;              // row sub-tile 0/1
    const int l15 = lane & 15;
    const int lhi = lane >> 4;

    // Preload B fragments (W): elem j -> k = ks*32 + lhi*8 + j, col = colHalf*64 + ct*16 + l15
    short8v bfrag[4][4];
    #pragma unroll
    for (int ks = 0; ks < 4; ++ks)
      #pragma unroll
      for (int ct = 0; ct < 4; ++ct) {
        const int col = colHalf * 64 + ct * 16 + l15;
        const int kb  = ks * 32 + lhi * 8;
        short8v f;
        #pragma unroll
        for (int j = 0; j < 8; ++j) f[j] = f2bf(W[(kb + j) * FDIM + col]);
        bfrag[ks][ct] = f;
      }

    const int nTiles = (nrows + 31) >> 5;
    for (int tile = blockIdx.x; tile < nTiles; tile += gridDim.x) {
        const int rowBase = tile * 32 + rowSub * 16;
        int arow = rowBase + l15;
        if (arow >= nrows) arow = nrows - 1;   // clamp: duplicate reads, stores guarded
        const float* xr = x + (size_t)arow * FDIM;
        f32x4 acc[4] = {};
        #pragma unroll
        for (int ks = 0; ks < 4; ++ks) {
            const int kb = ks * 32 + lhi * 8;
            float4 xa = *(const float4*)&xr[kb];
            float4 xb = *(const float4*)&xr[kb + 4];
            short8v af;
            af[0] = f2bf(xa.x); af[1] = f2bf(xa.y); af[2] = f2bf(xa.z); af[3] = f2bf(xa.w);
            af[4] = f2bf(xb.x); af[5] = f2bf(xb.y); af[6] = f2bf(xb.z); af[7] = f2bf(xb.w);
            #pragma unroll
            for (int ct = 0; ct < 4; ++ct)
                acc[ct] = __builtin_amdgcn_mfma_f32_16x16x32_bf16(af, bfrag[ks][ct], acc[ct], 0, 0, 0);
        }
        // D: row = rowBase + lhi*4 + r, col = colHalf*64 + ct*16 + l15
        #pragma unroll
        for (int ct = 0; ct < 4; ++ct) {
            const int col = colHalf * 64 + ct * 16 + l15;
            #pragma unroll
            for (int r = 0; r < 4; ++r) {
                int orow = rowBase + lhi * 4 + r;
                if (orow < nrows) y[(size_t)orow * FDIM + col] = (unsigned short)f2bf(acc[ct][r]);
            }
        }
    }
}

// ---- counting-sort pipeline ------------------------------------------------

__global__ __launch_bounds__(256)
void edge_histogram(const int* __restrict__ row, int* __restrict__ counts, int E) {
    int i = blockIdx.x * 256 + threadIdx.x;
    if (i < E) atomicAdd(&counts[row[i]], 1);
}

// Single-workgroup scan, per-thread contiguous chunks.  Thread t sums
// counts[t*per .. t*per+per), block-scans the 1024 sums, then walks its chunk
// again writing exclusive prefixes.  One block => no inter-block races
// (the property that made round-2/4's scan replay-stable).
__global__ __launch_bounds__(1024)
void scan_counts_fast(const int* __restrict__ counts, int* __restrict__ offsets,
                      int* __restrict__ cursor, int n) {
    const int tid = threadIdx.x;
    const int per = (n + 1023) >> 10;
    const int lo  = tid * per;
    const int hi  = (lo + per < n) ? lo + per : n;
    int s = 0;
    for (int i = lo; i < hi; ++i) s += counts[i];
    __shared__ int lds[1024];
    lds[tid] = s;
    __syncthreads();
    #pragma unroll
    for (int off = 1; off < 1024; off <<= 1) {
        int t = (tid >= off) ? lds[tid - off] : 0;
        __syncthreads();
        lds[tid] += t;
        __syncthreads();
    }
    int run = lds[tid] - s;                    // exclusive prefix of this chunk
    for (int i = lo; i < hi; ++i) {
        int c = counts[i];
        offsets[i] = run;
        cursor[i]  = run;
        run += c;
    }
    if (tid == 1023) offsets[n] = lds[1023];   // total = E
}

// Chunked XCD-affine scatter: chunk = row / rowsPerChunk; blocks with
// blockIdx%8 == chunk process only that chunk's rows, so each ~3.2MB skv
// window is written from (mostly) one XCD's L2 -> full-line evictions.
__global__ __launch_bounds__(256)
void edge_scatter_chunked(const int* __restrict__ row, const int* __restrict__ col,
                          const float* __restrict__ vals, int* __restrict__ cursor,
                          int2* __restrict__ skv, int E, int rowsPerChunk) {
    const int chunk = blockIdx.x & 7;
    const int sub   = blockIdx.x >> 3;
    const int nsub  = gridDim.x >> 3;
    const int lo = chunk * rowsPerChunk;
    const int hi = lo + rowsPerChunk;
    for (int i = sub * 256 + threadIdx.x; i < E; i += nsub * 256) {
        int r = row[i];
        if (r >= lo && r < hi) {
            int pos = atomicAdd(&cursor[r], 1);
            skv[pos] = make_int2(col[i], __float_as_int(vals[i]));
        }
    }
}

// ---- one wave per row, y in bf16, 2 edges in flight ------------------------
__global__ __launch_bounds__(256)
void spmm_csr_bf16(const int* __restrict__ offsets, const int2* __restrict__ skv,
                   const unsigned* __restrict__ yu, float* __restrict__ out, int N) {
    const int wid  = (blockIdx.x * 256 + threadIdx.x) >> 6;
    const int lane = threadIdx.x & 63;
    if (wid >= N) return;
    const int s = offsets[wid], t = offsets[wid + 1];
    float a0 = 0.f, a1 = 0.f, b0 = 0.f, b1 = 0.f;
    int e = s;
    for (; e + 2 <= t; e += 2) {
        int2 k0 = skv[e], k1 = skv[e + 1];
        unsigned u0 = yu[(size_t)k0.x * 64 + lane];
        unsigned u1 = yu[(size_t)k1.x * 64 + lane];
        float v0 = __int_as_float(k0.y), v1 = __int_as_float(k1.y);
        a0 = fmaf(v0, __uint_as_float(u0 << 16), a0);
        a1 = fmaf(v0, __uint_as_float(u0 & 0xffff0000u), a1);
        b0 = fmaf(v1, __uint_as_float(u1 << 16), b0);
        b1 = fmaf(v1, __uint_as_float(u1 & 0xffff0000u), b1);
    }
    if (e < t) {
        int2 k0 = skv[e];
        unsigned u0 = yu[(size_t)k0.x * 64 + lane];
        float v0 = __int_as_float(k0.y);
        a0 = fmaf(v0, __uint_as_float(u0 << 16), a0);
        a1 = fmaf(v0, __uint_as_float(u0 & 0xffff0000u), a1);
    }
    *(float2*)&out[(size_t)wid * FDIM + lane * 2] = make_float2(a0 + b0, a1 + b1);
}

// ---- fallbacks (round-1 path, never taken when ws is large enough) ---------

__global__ __launch_bounds__(256)
void gemm_rows(const float* src, const float* __restrict__ W, float* dst, int nrows) {
    __shared__ float sW[FDIM * FDIM];
    for (int i = threadIdx.x; i < FDIM * FDIM; i += 256) sW[i] = W[i];
    __syncthreads();
    const int lane = threadIdx.x & 63;
    const int wid  = (blockIdx.x * 256 + threadIdx.x) >> 6;
    const int nw   = (gridDim.x * 256) >> 6;
    for (int n = wid; n < nrows; n += nw) {
        const float* xr = src + (size_t)n * FDIM;
        float acc0 = 0.f, acc1 = 0.f;
        #pragma unroll 8
        for (int k = 0; k < FDIM; ++k) {
            float xv = xr[k];
            float2 w = *(const float2*)&sW[k * FDIM + lane * 2];
            acc0 = fmaf(xv, w.x, acc0);
            acc1 = fmaf(xv, w.y, acc1);
        }
        *(float2*)&dst[(size_t)n * FDIM + lane * 2] = make_float2(acc0, acc1);
    }
}

__global__ __launch_bounds__(256)
void spmm_scatter(const int* __restrict__ row, const int* __restrict__ col,
                  const float* __restrict__ vals, const float* __restrict__ y,
                  float* __restrict__ out, int E) {
    long long tid = (long long)blockIdx.x * 256 + threadIdx.x;
    int e = (int)(tid >> 5);
    if (e >= E) return;
    int c = ((int)tid & 31) << 2;
    int r  = row[e];
    int cl = col[e];
    float v = vals[e];
    float4 yv = *(const float4*)&y[(size_t)cl * FDIM + c];
    float* po = out + (size_t)r * FDIM + c;
    unsafeAtomicAdd(po + 0, v * yv.x);
    unsafeAtomicAdd(po + 1, v * yv.y);
    unsafeAtomicAdd(po + 2, v * yv.z);
    unsafeAtomicAdd(po + 3, v * yv.w);
}

extern "C" void kernel_launch(void* const* d_in, const int* in_sizes, int n_in,
                              void* d_out, int out_size, void* d_ws, size_t ws_size,
                              hipStream_t stream) {
    const int*   row  = (const int*)d_in[0];
    const int*   col  = (const int*)d_in[1];
    const float* vals = (const float*)d_in[2];
    const float* x    = (const float*)d_in[3];
    const float* W    = (const float*)d_in[4];
    float* out = (float*)d_out;

    const int E = in_sizes[0];
    const int N = in_sizes[3] / FDIM;

    // workspace layout (fast path)
    char* p = (char*)d_ws;
    unsigned short* yb = (unsigned short*)p;  p += (size_t)N * FDIM * 2;   // y bf16
    int*   counts   = (int*)p;   p += (size_t)N * 4;
    int*   offsets  = (int*)p;   p += (size_t)(N + 1) * 4 + 12;            // keep 16B align
    int*   cursor   = (int*)p;   p += (size_t)N * 4;
    int2*  skv      = (int2*)p;  p += (size_t)E * 8;
    const size_t need_fast = (size_t)(p - (char*)d_ws);

    const int eb = (E + 255) / 256;
    const int rowsPerChunk = (N + 7) / 8;

    if (ws_size >= need_fast) {
        hipMemsetAsync(counts, 0, (size_t)N * 4, stream);
        gemm_mfma<<<512, 256, 0, stream>>>(x, W, yb, N);
        edge_histogram<<<eb, 256, 0, stream>>>(row, counts, E);
        scan_counts_fast<<<1, 1024, 0, stream>>>(counts, offsets, cursor, N);
        edge_scatter_chunked<<<2048, 256, 0, stream>>>(row, col, vals, cursor, skv, E, rowsPerChunk);
        spmm_csr_bf16<<<((size_t)N * 64 + 255) / 256, 256, 0, stream>>>(offsets, skv, (const unsigned*)yb, out, N);
    } else if (ws_size >= (size_t)N * FDIM * 4) {
        float* yw = (float*)d_ws;
        hipMemsetAsync(d_out, 0, (size_t)out_size * sizeof(float), stream);
        gemm_rows<<<1024, 256, 0, stream>>>(x, W, yw, N);
        spmm_scatter<<<(E + 7) / 8, 256, 0, stream>>>(row, col, vals, yw, out, E);
    } else {
        hipMemsetAsync(d_out, 0, (size_t)out_size * sizeof(float), stream);
        spmm_scatter<<<(E + 7) / 8, 256, 0, stream>>>(row, col, vals, x, out, E);
        gemm_rows<<<1024, 256, 0, stream>>>(out, W, out, N);
    }
}

// Round 7
// 497.559 us; speedup vs baseline: 1.3731x; 1.3731x over previous
//
#include <hip/hip_runtime.h>
#include <hip/hip_bf16.h>

#define FDIM 128

typedef __attribute__((ext_vector_type(8))) short short8v;   // 8 bf16 in 4 VGPRs
typedef __attribute__((ext_vector_type(4))) float f32x4;

__device__ __forceinline__ short f2bf(float f) {             // RNE f32 -> bf16 bits
    unsigned u = __float_as_uint(f);
    u += 0x7FFFu + ((u >> 16) & 1u);
    return (short)(u >> 16);
}

// ---- y = x @ W via MFMA bf16.  Wave: 16 rows x 64 cols; block: 32 rows x 128 cols.
__global__ __launch_bounds__(256)
void gemm_mfma(const float* __restrict__ x, const float* __restrict__ W,
               unsigned short* __restrict__ y, int nrows) {
    const int lane = threadIdx.x & 63;
    const int wid  = threadIdx.x >> 6;         // 0..3
    const int colHalf = wid & 1;               // cols 0-63 / 64-127
    const int rowSub  = wid >> 1;              // row sub-tile 0/1
    const int l15 = lane & 15;
    const int lhi = lane >> 4;

    short8v bfrag[4][4];
    #pragma unroll
    for (int ks = 0; ks < 4; ++ks)
      #pragma unroll
      for (int ct = 0; ct < 4; ++ct) {
        const int col = colHalf * 64 + ct * 16 + l15;
        const int kb  = ks * 32 + lhi * 8;
        short8v f;
        #pragma unroll
        for (int j = 0; j < 8; ++j) f[j] = f2bf(W[(kb + j) * FDIM + col]);
        bfrag[ks][ct] = f;
      }

    const int nTiles = (nrows + 31) >> 5;
    for (int tile = blockIdx.x; tile < nTiles; tile += gridDim.x) {
        const int rowBase = tile * 32 + rowSub * 16;
        int arow = rowBase + l15;
        if (arow >= nrows) arow = nrows - 1;   // clamp: duplicate reads, stores guarded
        const float* xr = x + (size_t)arow * FDIM;
        f32x4 acc[4] = {};
        #pragma unroll
        for (int ks = 0; ks < 4; ++ks) {
            const int kb = ks * 32 + lhi * 8;
            float4 xa = *(const float4*)&xr[kb];
            float4 xb = *(const float4*)&xr[kb + 4];
            short8v af;
            af[0] = f2bf(xa.x); af[1] = f2bf(xa.y); af[2] = f2bf(xa.z); af[3] = f2bf(xa.w);
            af[4] = f2bf(xb.x); af[5] = f2bf(xb.y); af[6] = f2bf(xb.z); af[7] = f2bf(xb.w);
            #pragma unroll
            for (int ct = 0; ct < 4; ++ct)
                acc[ct] = __builtin_amdgcn_mfma_f32_16x16x32_bf16(af, bfrag[ks][ct], acc[ct], 0, 0, 0);
        }
        #pragma unroll
        for (int ct = 0; ct < 4; ++ct) {
            const int col = colHalf * 64 + ct * 16 + l15;
            #pragma unroll
            for (int r = 0; r < 4; ++r) {
                int orow = rowBase + lhi * 4 + r;
                if (orow < nrows) y[(size_t)orow * FDIM + col] = (unsigned short)f2bf(acc[ct][r]);
            }
        }
    }
}

// ---- counting-sort pipeline ------------------------------------------------

__global__ __launch_bounds__(256)
void edge_histogram(const int* __restrict__ row, int* __restrict__ counts, int E) {
    int i = blockIdx.x * 256 + threadIdx.x;
    if (i < E) atomicAdd(&counts[row[i]], 1);
}

// Single-workgroup scan v2: coalesced int4 tiles + shfl wave-scan.
// 1024 threads, tile = 4096 elements, 3 barriers/tile, one block => replay-safe.
__global__ __launch_bounds__(1024)
void scan_counts_v2(const int* __restrict__ counts, int* __restrict__ offsets,
                    int* __restrict__ cursor, int n) {
    const int tid  = threadIdx.x;
    const int lane = tid & 63;
    const int wv   = tid >> 6;                  // 0..15
    __shared__ int waveSum[16];
    int carry = 0;
    const int nTiles = (n + 4095) >> 12;
    for (int tile = 0; tile < nTiles; ++tile) {
        const int idx = tile * 4096 + tid * 4;
        int4 v = make_int4(0, 0, 0, 0);
        if (idx + 3 < n) v = *(const int4*)&counts[idx];
        else if (idx < n) {
            v.x = counts[idx];
            if (idx + 1 < n) v.y = counts[idx + 1];
            if (idx + 2 < n) v.z = counts[idx + 2];
        }
        int s4 = v.x + v.y + v.z + v.w;
        // wave-inclusive scan of s4
        int s = s4;
        #pragma unroll
        for (int off = 1; off < 64; off <<= 1) {
            int t = __shfl_up(s, off, 64);
            if (lane >= off) s += t;
        }
        if (lane == 63) waveSum[wv] = s;
        __syncthreads();
        if (tid < 64) {                          // wave 0 scans the 16 wave sums
            int ws = (tid < 16) ? waveSum[tid] : 0;
            #pragma unroll
            for (int off = 1; off < 16; off <<= 1) {
                int t = __shfl_up(ws, off, 64);
                if (lane >= off) ws += t;
            }
            if (tid < 16) waveSum[tid] = ws;     // inclusive wave prefix
        }
        __syncthreads();
        const int waveBase = (wv == 0) ? 0 : waveSum[wv - 1];
        const int tileTot  = waveSum[15];
        int incl = s + waveBase + carry;         // inclusive prefix incl. carry
        int e0 = incl - s4;
        int4 o = make_int4(e0, e0 + v.x, e0 + v.x + v.y, e0 + v.x + v.y + v.z);
        if (idx + 3 < n) {
            *(int4*)&offsets[idx] = o;
            *(int4*)&cursor[idx]  = o;
        } else if (idx < n) {
            offsets[idx] = o.x;  cursor[idx] = o.x;
            if (idx + 1 < n) { offsets[idx + 1] = o.y; cursor[idx + 1] = o.y; }
            if (idx + 2 < n) { offsets[idx + 2] = o.z; cursor[idx + 2] = o.z; }
        }
        carry += tileTot;
        __syncthreads();                          // waveSum reused next tile
    }
    if (tid == 0) offsets[n] = carry;             // = E
}

// Chunked XCD-affine scatter (round-5, proven).
__global__ __launch_bounds__(256)
void edge_scatter_chunked(const int* __restrict__ row, const int* __restrict__ col,
                          const float* __restrict__ vals, int* __restrict__ cursor,
                          int2* __restrict__ skv, int E, int rowsPerChunk) {
    const int chunk = blockIdx.x & 7;
    const int sub   = blockIdx.x >> 3;
    const int nsub  = gridDim.x >> 3;
    const int lo = chunk * rowsPerChunk;
    const int hi = lo + rowsPerChunk;
    for (int i = sub * 256 + threadIdx.x; i < E; i += nsub * 256) {
        int r = row[i];
        if (r >= lo && r < hi) {
            int pos = atomicAdd(&cursor[r], 1);
            skv[pos] = make_int2(col[i], __float_as_int(vals[i]));
        }
    }
}

// ---- one wave per row, y in bf16, 2 edges in flight ------------------------
__global__ __launch_bounds__(256)
void spmm_csr_bf16(const int* __restrict__ offsets, const int2* __restrict__ skv,
                   const unsigned* __restrict__ yu, float* __restrict__ out, int N) {
    const int wid  = (blockIdx.x * 256 + threadIdx.x) >> 6;
    const int lane = threadIdx.x & 63;
    if (wid >= N) return;
    const int s = offsets[wid], t = offsets[wid + 1];
    float a0 = 0.f, a1 = 0.f, b0 = 0.f, b1 = 0.f;
    int e = s;
    for (; e + 2 <= t; e += 2) {
        int2 k0 = skv[e], k1 = skv[e + 1];
        unsigned u0 = yu[(size_t)k0.x * 64 + lane];
        unsigned u1 = yu[(size_t)k1.x * 64 + lane];
        float v0 = __int_as_float(k0.y), v1 = __int_as_float(k1.y);
        a0 = fmaf(v0, __uint_as_float(u0 << 16), a0);
        a1 = fmaf(v0, __uint_as_float(u0 & 0xffff0000u), a1);
        b0 = fmaf(v1, __uint_as_float(u1 << 16), b0);
        b1 = fmaf(v1, __uint_as_float(u1 & 0xffff0000u), b1);
    }
    if (e < t) {
        int2 k0 = skv[e];
        unsigned u0 = yu[(size_t)k0.x * 64 + lane];
        float v0 = __int_as_float(k0.y);
        a0 = fmaf(v0, __uint_as_float(u0 << 16), a0);
        a1 = fmaf(v0, __uint_as_float(u0 & 0xffff0000u), a1);
    }
    *(float2*)&out[(size_t)wid * FDIM + lane * 2] = make_float2(a0 + b0, a1 + b1);
}

// ---- fallbacks (round-1 path, never taken when ws is large enough) ---------

__global__ __launch_bounds__(256)
void gemm_rows(const float* src, const float* __restrict__ W, float* dst, int nrows) {
    __shared__ float sW[FDIM * FDIM];
    for (int i = threadIdx.x; i < FDIM * FDIM; i += 256) sW[i] = W[i];
    __syncthreads();
    const int lane = threadIdx.x & 63;
    const int wid  = (blockIdx.x * 256 + threadIdx.x) >> 6;
    const int nw   = (gridDim.x * 256) >> 6;
    for (int n = wid; n < nrows; n += nw) {
        const float* xr = src + (size_t)n * FDIM;
        float acc0 = 0.f, acc1 = 0.f;
        #pragma unroll 8
        for (int k = 0; k < FDIM; ++k) {
            float xv = xr[k];
            float2 w = *(const float2*)&sW[k * FDIM + lane * 2];
            acc0 = fmaf(xv, w.x, acc0);
            acc1 = fmaf(xv, w.y, acc1);
        }
        *(float2*)&dst[(size_t)n * FDIM + lane * 2] = make_float2(acc0, acc1);
    }
}

__global__ __launch_bounds__(256)
void spmm_scatter(const int* __restrict__ row, const int* __restrict__ col,
                  const float* __restrict__ vals, const float* __restrict__ y,
                  float* __restrict__ out, int E) {
    long long tid = (long long)blockIdx.x * 256 + threadIdx.x;
    int e = (int)(tid >> 5);
    if (e >= E) return;
    int c = ((int)tid & 31) << 2;
    int r  = row[e];
    int cl = col[e];
    float v = vals[e];
    float4 yv = *(const float4*)&y[(size_t)cl * FDIM + c];
    float* po = out + (size_t)r * FDIM + c;
    unsafeAtomicAdd(po + 0, v * yv.x);
    unsafeAtomicAdd(po + 1, v * yv.y);
    unsafeAtomicAdd(po + 2, v * yv.z);
    unsafeAtomicAdd(po + 3, v * yv.w);
}

extern "C" void kernel_launch(void* const* d_in, const int* in_sizes, int n_in,
                              void* d_out, int out_size, void* d_ws, size_t ws_size,
                              hipStream_t stream) {
    const int*   row  = (const int*)d_in[0];
    const int*   col  = (const int*)d_in[1];
    const float* vals = (const float*)d_in[2];
    const float* x    = (const float*)d_in[3];
    const float* W    = (const float*)d_in[4];
    float* out = (float*)d_out;

    const int E = in_sizes[0];
    const int N = in_sizes[3] / FDIM;

    // workspace layout (fast path); 16B alignment of counts/offsets/cursor holds
    // for N*FDIM*2 and (N+1)*4+12 with N=100000 (all multiples of 16).
    char* p = (char*)d_ws;
    unsigned short* yb = (unsigned short*)p;  p += (size_t)N * FDIM * 2;   // y bf16
    int*   counts   = (int*)p;   p += (size_t)N * 4;
    int*   offsets  = (int*)p;   p += (size_t)(N + 1) * 4 + 12;
    int*   cursor   = (int*)p;   p += (size_t)N * 4;
    int2*  skv      = (int2*)p;  p += (size_t)E * 8;
    const size_t need_fast = (size_t)(p - (char*)d_ws);

    const int eb = (E + 255) / 256;
    const int rowsPerChunk = (N + 7) / 8;

    if (ws_size >= need_fast) {
        hipMemsetAsync(counts, 0, (size_t)N * 4, stream);
        gemm_mfma<<<512, 256, 0, stream>>>(x, W, yb, N);
        edge_histogram<<<eb, 256, 0, stream>>>(row, counts, E);
        scan_counts_v2<<<1, 1024, 0, stream>>>(counts, offsets, cursor, N);
        edge_scatter_chunked<<<2048, 256, 0, stream>>>(row, col, vals, cursor, skv, E, rowsPerChunk);
        spmm_csr_bf16<<<((size_t)N * 64 + 255) / 256, 256, 0, stream>>>(offsets, skv, (const unsigned*)yb, out, N);
    } else if (ws_size >= (size_t)N * FDIM * 4) {
        float* yw = (float*)d_ws;
        hipMemsetAsync(d_out, 0, (size_t)out_size * sizeof(float), stream);
        gemm_rows<<<1024, 256, 0, stream>>>(x, W, yw, N);
        spmm_scatter<<<(E + 7) / 8, 256, 0, stream>>>(row, col, vals, yw, out, E);
    } else {
        hipMemsetAsync(d_out, 0, (size_t)out_size * sizeof(float), stream);
        spmm_scatter<<<(E + 7) / 8, 256, 0, stream>>>(row, col, vals, x, out, E);
        gemm_rows<<<1024, 256, 0, stream>>>(out, W, out, N);
    }
}

// Round 8
// 435.531 us; speedup vs baseline: 1.5687x; 1.1424x over previous
//
#include <hip/hip_runtime.h>
#include <hip/hip_bf16.h>

#define FDIM 128

typedef __attribute__((ext_vector_type(8))) short short8v;   // 8 bf16 in 4 VGPRs
typedef __attribute__((ext_vector_type(4))) float f32x4;
typedef __attribute__((ext_vector_type(4))) unsigned uint4v;

__device__ __forceinline__ short f2bf(float f) {             // RNE f32 -> bf16 bits
    unsigned u = __float_as_uint(f);
    u += 0x7FFFu + ((u >> 16) & 1u);
    return (short)(u >> 16);
}

// ---- y = x @ W via MFMA bf16.  Wave: 16 rows x 64 cols; block: 32 rows x 128 cols.
__global__ __launch_bounds__(256)
void gemm_mfma(const float* __restrict__ x, const float* __restrict__ W,
               unsigned short* __restrict__ y, int nrows) {
    const int lane = threadIdx.x & 63;
    const int wid  = threadIdx.x >> 6;         // 0..3
    const int colHalf = wid & 1;               // cols 0-63 / 64-127
    const int rowSub  = wid >> 1;              // row sub-tile 0/1
    const int l15 = lane & 15;
    const int lhi = lane >> 4;

    short8v bfrag[4][4];
    #pragma unroll
    for (int ks = 0; ks < 4; ++ks)
      #pragma unroll
      for (int ct = 0; ct < 4; ++ct) {
        const int col = colHalf * 64 + ct * 16 + l15;
        const int kb  = ks * 32 + lhi * 8;
        short8v f;
        #pragma unroll
        for (int j = 0; j < 8; ++j) f[j] = f2bf(W[(kb + j) * FDIM + col]);
        bfrag[ks][ct] = f;
      }

    const int nTiles = (nrows + 31) >> 5;
    for (int tile = blockIdx.x; tile < nTiles; tile += gridDim.x) {
        const int rowBase = tile * 32 + rowSub * 16;
        int arow = rowBase + l15;
        if (arow >= nrows) arow = nrows - 1;   // clamp: duplicate reads, stores guarded
        const float* xr = x + (size_t)arow * FDIM;
        f32x4 acc[4] = {};
        #pragma unroll
        for (int ks = 0; ks < 4; ++ks) {
            const int kb = ks * 32 + lhi * 8;
            float4 xa = *(const float4*)&xr[kb];
            float4 xb = *(const float4*)&xr[kb + 4];
            short8v af;
            af[0] = f2bf(xa.x); af[1] = f2bf(xa.y); af[2] = f2bf(xa.z); af[3] = f2bf(xa.w);
            af[4] = f2bf(xb.x); af[5] = f2bf(xb.y); af[6] = f2bf(xb.z); af[7] = f2bf(xb.w);
            #pragma unroll
            for (int ct = 0; ct < 4; ++ct)
                acc[ct] = __builtin_amdgcn_mfma_f32_16x16x32_bf16(af, bfrag[ks][ct], acc[ct], 0, 0, 0);
        }
        #pragma unroll
        for (int ct = 0; ct < 4; ++ct) {
            const int col = colHalf * 64 + ct * 16 + l15;
            #pragma unroll
            for (int r = 0; r < 4; ++r) {
                int orow = rowBase + lhi * 4 + r;
                if (orow < nrows) y[(size_t)orow * FDIM + col] = (unsigned short)f2bf(acc[ct][r]);
            }
        }
    }
}

// ---- counting-sort pipeline ------------------------------------------------

__global__ __launch_bounds__(256)
void edge_histogram(const int* __restrict__ row, int* __restrict__ counts, int E) {
    int i = blockIdx.x * 256 + threadIdx.x;
    if (i < E) atomicAdd(&counts[row[i]], 1);
}

// Single-workgroup scan v2: coalesced int4 tiles + shfl wave-scan (round-7, proven).
__global__ __launch_bounds__(1024)
void scan_counts_v2(const int* __restrict__ counts, int* __restrict__ offsets,
                    int* __restrict__ cursor, int n) {
    const int tid  = threadIdx.x;
    const int lane = tid & 63;
    const int wv   = tid >> 6;                  // 0..15
    __shared__ int waveSum[16];
    int carry = 0;
    const int nTiles = (n + 4095) >> 12;
    for (int tile = 0; tile < nTiles; ++tile) {
        const int idx = tile * 4096 + tid * 4;
        int4 v = make_int4(0, 0, 0, 0);
        if (idx + 3 < n) v = *(const int4*)&counts[idx];
        else if (idx < n) {
            v.x = counts[idx];
            if (idx + 1 < n) v.y = counts[idx + 1];
            if (idx + 2 < n) v.z = counts[idx + 2];
        }
        int s4 = v.x + v.y + v.z + v.w;
        int s = s4;
        #pragma unroll
        for (int off = 1; off < 64; off <<= 1) {
            int t = __shfl_up(s, off, 64);
            if (lane >= off) s += t;
        }
        if (lane == 63) waveSum[wv] = s;
        __syncthreads();
        if (tid < 64) {
            int ws = (tid < 16) ? waveSum[tid] : 0;
            #pragma unroll
            for (int off = 1; off < 16; off <<= 1) {
                int t = __shfl_up(ws, off, 64);
                if (lane >= off) ws += t;
            }
            if (tid < 16) waveSum[tid] = ws;
        }
        __syncthreads();
        const int waveBase = (wv == 0) ? 0 : waveSum[wv - 1];
        const int tileTot  = waveSum[15];
        int incl = s + waveBase + carry;
        int e0 = incl - s4;
        int4 o = make_int4(e0, e0 + v.x, e0 + v.x + v.y, e0 + v.x + v.y + v.z);
        if (idx + 3 < n) {
            *(int4*)&offsets[idx] = o;
            *(int4*)&cursor[idx]  = o;
        } else if (idx < n) {
            offsets[idx] = o.x;  cursor[idx] = o.x;
            if (idx + 1 < n) { offsets[idx + 1] = o.y; cursor[idx + 1] = o.y; }
            if (idx + 2 < n) { offsets[idx + 2] = o.z; cursor[idx + 2] = o.z; }
        }
        carry += tileTot;
        __syncthreads();
    }
    if (tid == 0) offsets[n] = carry;             // = E
}

// Chunked XCD-affine scatter (round-5, proven).
__global__ __launch_bounds__(256)
void edge_scatter_chunked(const int* __restrict__ row, const int* __restrict__ col,
                          const float* __restrict__ vals, int* __restrict__ cursor,
                          int2* __restrict__ skv, int E, int rowsPerChunk) {
    const int chunk = blockIdx.x & 7;
    const int sub   = blockIdx.x >> 3;
    const int nsub  = gridDim.x >> 3;
    const int lo = chunk * rowsPerChunk;
    const int hi = lo + rowsPerChunk;
    for (int i = sub * 256 + threadIdx.x; i < E; i += nsub * 256) {
        int r = row[i];
        if (r >= lo && r < hi) {
            int pos = atomicAdd(&cursor[r], 1);
            skv[pos] = make_int2(col[i], __float_as_int(vals[i]));
        }
    }
}

// ---- spmm v2: 16 lanes/edge, 4 edges per load instr, 8 edges in flight -----
// Lane l (group g = l>>4, p = l&15) accumulates features [p*8, p*8+8) for its
// group's edge subset; cross-group reduce via shfl_xor(16|32); group 0 stores.
__global__ __launch_bounds__(256)
void spmm_csr_v2(const int* __restrict__ offsets, const int2* __restrict__ skv,
                 const unsigned* __restrict__ yu, float* __restrict__ out, int N) {
    const int wid  = (blockIdx.x * 256 + threadIdx.x) >> 6;   // row
    const int lane = threadIdx.x & 63;
    if (wid >= N) return;
    const int l15 = lane & 15;
    const int grp = lane >> 4;           // 0..3
    const int s = offsets[wid], t = offsets[wid + 1];

    float accA[8] = {0,0,0,0,0,0,0,0};
    float accB[8] = {0,0,0,0,0,0,0,0};

    int e = s;
    for (; e + 8 <= t; e += 8) {
        int2 kA = skv[e + grp];
        int2 kB = skv[e + 4 + grp];
        uint4v uA = *(const uint4v*)&yu[(size_t)kA.x * 64 + l15 * 4];
        uint4v uB = *(const uint4v*)&yu[(size_t)kB.x * 64 + l15 * 4];
        float vA = __int_as_float(kA.y);
        float vB = __int_as_float(kB.y);
        #pragma unroll
        for (int j = 0; j < 4; ++j) {
            accA[2*j]   = fmaf(vA, __uint_as_float(uA[j] << 16),          accA[2*j]);
            accA[2*j+1] = fmaf(vA, __uint_as_float(uA[j] & 0xffff0000u), accA[2*j+1]);
            accB[2*j]   = fmaf(vB, __uint_as_float(uB[j] << 16),          accB[2*j]);
            accB[2*j+1] = fmaf(vB, __uint_as_float(uB[j] & 0xffff0000u), accB[2*j+1]);
        }
    }
    for (; e < t; e += 4) {                       // tail, predicated
        int eA = e + grp;
        bool ok = eA < t;
        int2 kA = ok ? skv[eA] : make_int2(0, 0);
        uint4v uA = *(const uint4v*)&yu[(size_t)kA.x * 64 + l15 * 4];
        float vA = ok ? __int_as_float(kA.y) : 0.f;
        #pragma unroll
        for (int j = 0; j < 4; ++j) {
            accA[2*j]   = fmaf(vA, __uint_as_float(uA[j] << 16),          accA[2*j]);
            accA[2*j+1] = fmaf(vA, __uint_as_float(uA[j] & 0xffff0000u), accA[2*j+1]);
        }
    }
    #pragma unroll
    for (int j = 0; j < 8; ++j) {
        float a = accA[j] + accB[j];
        a += __shfl_xor(a, 16, 64);
        a += __shfl_xor(a, 32, 64);
        accA[j] = a;
    }
    if (grp == 0) {
        float* po = out + (size_t)wid * FDIM + l15 * 8;
        *(float4*)po       = make_float4(accA[0], accA[1], accA[2], accA[3]);
        *(float4*)(po + 4) = make_float4(accA[4], accA[5], accA[6], accA[7]);
    }
}

// ---- fallbacks (round-1 path, never taken when ws is large enough) ---------

__global__ __launch_bounds__(256)
void gemm_rows(const float* src, const float* __restrict__ W, float* dst, int nrows) {
    __shared__ float sW[FDIM * FDIM];
    for (int i = threadIdx.x; i < FDIM * FDIM; i += 256) sW[i] = W[i];
    __syncthreads();
    const int lane = threadIdx.x & 63;
    const int wid  = (blockIdx.x * 256 + threadIdx.x) >> 6;
    const int nw   = (gridDim.x * 256) >> 6;
    for (int n = wid; n < nrows; n += nw) {
        const float* xr = src + (size_t)n * FDIM;
        float acc0 = 0.f, acc1 = 0.f;
        #pragma unroll 8
        for (int k = 0; k < FDIM; ++k) {
            float xv = xr[k];
            float2 w = *(const float2*)&sW[k * FDIM + lane * 2];
            acc0 = fmaf(xv, w.x, acc0);
            acc1 = fmaf(xv, w.y, acc1);
        }
        *(float2*)&dst[(size_t)n * FDIM + lane * 2] = make_float2(acc0, acc1);
    }
}

__global__ __launch_bounds__(256)
void spmm_scatter(const int* __restrict__ row, const int* __restrict__ col,
                  const float* __restrict__ vals, const float* __restrict__ y,
                  float* __restrict__ out, int E) {
    long long tid = (long long)blockIdx.x * 256 + threadIdx.x;
    int e = (int)(tid >> 5);
    if (e >= E) return;
    int c = ((int)tid & 31) << 2;
    int r  = row[e];
    int cl = col[e];
    float v = vals[e];
    float4 yv = *(const float4*)&y[(size_t)cl * FDIM + c];
    float* po = out + (size_t)r * FDIM + c;
    unsafeAtomicAdd(po + 0, v * yv.x);
    unsafeAtomicAdd(po + 1, v * yv.y);
    unsafeAtomicAdd(po + 2, v * yv.z);
    unsafeAtomicAdd(po + 3, v * yv.w);
}

extern "C" void kernel_launch(void* const* d_in, const int* in_sizes, int n_in,
                              void* d_out, int out_size, void* d_ws, size_t ws_size,
                              hipStream_t stream) {
    const int*   row  = (const int*)d_in[0];
    const int*   col  = (const int*)d_in[1];
    const float* vals = (const float*)d_in[2];
    const float* x    = (const float*)d_in[3];
    const float* W    = (const float*)d_in[4];
    float* out = (float*)d_out;

    const int E = in_sizes[0];
    const int N = in_sizes[3] / FDIM;

    // workspace layout (fast path); all offsets 16B-aligned for N=100000.
    char* p = (char*)d_ws;
    unsigned short* yb = (unsigned short*)p;  p += (size_t)N * FDIM * 2;   // y bf16
    int*   counts   = (int*)p;   p += (size_t)N * 4;
    int*   offsets  = (int*)p;   p += (size_t)(N + 1) * 4 + 12;
    int*   cursor   = (int*)p;   p += (size_t)N * 4;
    int2*  skv      = (int2*)p;  p += (size_t)E * 8;
    const size_t need_fast = (size_t)(p - (char*)d_ws);

    const int eb = (E + 255) / 256;
    const int rowsPerChunk = (N + 7) / 8;

    if (ws_size >= need_fast) {
        hipMemsetAsync(counts, 0, (size_t)N * 4, stream);
        gemm_mfma<<<512, 256, 0, stream>>>(x, W, yb, N);
        edge_histogram<<<eb, 256, 0, stream>>>(row, counts, E);
        scan_counts_v2<<<1, 1024, 0, stream>>>(counts, offsets, cursor, N);
        edge_scatter_chunked<<<2048, 256, 0, stream>>>(row, col, vals, cursor, skv, E, rowsPerChunk);
        spmm_csr_v2<<<((size_t)N * 64 + 255) / 256, 256, 0, stream>>>(offsets, skv, (const unsigned*)yb, out, N);
    } else if (ws_size >= (size_t)N * FDIM * 4) {
        float* yw = (float*)d_ws;
        hipMemsetAsync(d_out, 0, (size_t)out_size * sizeof(float), stream);
        gemm_rows<<<1024, 256, 0, stream>>>(x, W, yw, N);
        spmm_scatter<<<(E + 7) / 8, 256, 0, stream>>>(row, col, vals, yw, out, E);
    } else {
        hipMemsetAsync(d_out, 0, (size_t)out_size * sizeof(float), stream);
        spmm_scatter<<<(E + 7) / 8, 256, 0, stream>>>(row, col, vals, x, out, E);
        gemm_rows<<<1024, 256, 0, stream>>>(out, W, out, N);
    }
}